// Round 17
// baseline (471.712 us; speedup 1.0000x reference)
//
#include <hip/hip_runtime.h>
#include <cstdint>

#define BB 4
#define NN 4096
#define EE 16384
#define DD 256
#define ADIM 64
#define TT 16
#define HALFE 8
#define STEPS 3
#define OSTRIDE 4160
#define MAXTILES 1088            // 128-row msg tiles (uniques <= 139264 padded worst case)
#define MAXM (MAXTILES * 128)

#define AS1 __attribute__((address_space(1)))
#define AS3 __attribute__((address_space(3)))

typedef __attribute__((ext_vector_type(8))) short short8;
typedef __attribute__((ext_vector_type(4))) float f32x4;

__device__ __forceinline__ float sigmoidf_(float x) { return 1.0f / (1.0f + __expf(-x)); }

__device__ __forceinline__ unsigned short f2bf(float x) {
    unsigned u = __float_as_uint(x);
    u += 0x7fffu + ((u >> 16) & 1u);
    return (unsigned short)(u >> 16);
}
__device__ __forceinline__ float bf2f(unsigned short b) {
    return __uint_as_float(((unsigned)b) << 16);
}

// ---------------- fused prep: init + conv(W2) + wcat + whh + zero(acc,counts,c32,map) ----------------
__global__ void prep_kernel(const int* __restrict__ ann_id, const float* __restrict__ type_embed,
                            const float* __restrict__ edge_embed, const float* __restrict__ Wr,
                            const float* __restrict__ Wz, const float* __restrict__ Wh,
                            float* __restrict__ ann, float* __restrict__ h,
                            unsigned short* __restrict__ hbf, unsigned short* __restrict__ Xbf,
                            unsigned short* __restrict__ W2bf, unsigned short* __restrict__ Wcatbf,
                            unsigned short* __restrict__ Whhbf, float* __restrict__ acc,
                            int* __restrict__ counts, int* __restrict__ c32,
                            int* __restrict__ map) {
    int bid = blockIdx.x, tid = threadIdx.x;
    if (bid < 4096) {                           // init: B*N*64 threads, 4 elems each
        if (bid < 128) counts[bid * 256 + tid] = 0;
        if (bid < 1024) map[bid * 256 + tid] = -1;
        if (bid == 0) { c32[tid] = 0; c32[256 + tid] = 0; c32[512 + tid] = 0; c32[768 + tid] = 0; }
        if (bid == 0 && tid < 16) acc[tid] = 0.f;
        int idx = bid * 256 + tid;
        int bn = idx >> 6, q = idx & 63;
        int id = ann_id[bn];
        float4 v = {0.f, 0.f, 0.f, 0.f};
        if (q < 16) {
            if (id > 0) v = ((const float4*)(type_embed + (size_t)(id - 1) * ADIM))[q];
            ((float4*)(ann + (size_t)bn * ADIM))[q] = v;
        }
        ((float4*)(h + (size_t)bn * DD))[q] = v;
        ushort4 o;
        o.x = f2bf(v.x); o.y = f2bf(v.y); o.z = f2bf(v.z); o.w = f2bf(v.w);
        ((ushort4*)(hbf + (size_t)bn * DD))[q] = o;
        ((ushort4*)(Xbf + (size_t)bn * 768 + 512))[q] = o;
    } else if (bid < 5120) {                    // conv edge_embed -> W2bf, 4 elems each
        int idx = (bid - 4096) * 256 + tid;
        float4 v = ((const float4*)edge_embed)[idx];
        ushort4 o;
        o.x = f2bf(v.x); o.y = f2bf(v.y); o.z = f2bf(v.z); o.w = f2bf(v.w);
        ((ushort4*)W2bf)[idx] = o;
    } else if (bid < 7424) {                    // Wcat_t[c][k]
        int idx = (bid - 5120) * 256 + tid;     // 768*768
        int c = idx / 768, k = idx % 768;
        float v;
        if (c < 256)       v = Wr[c * 768 + k];
        else if (c < 512)  v = Wz[(c - 256) * 768 + k];
        else               v = (k < 512) ? Wh[(c - 512) * 768 + k] : 0.f;
        Wcatbf[idx] = f2bf(v);
    } else {                                    // Whh_t[i][k] = Wh[i][512+k]
        int idx = (bid - 7424) * 256 + tid;     // 256*256
        int i = idx / 256, k = idx % 256;
        Whhbf[idx] = f2bf(Wh[i * 768 + 512 + k]);
    }
}

// ---------------- claim: node-degree counts + dedup-claim unique (b,t16,nbr) keys ----------------
__global__ void claim_kernel(const int* __restrict__ src, const int* __restrict__ dst,
                             const int* __restrict__ et, int* __restrict__ counts,
                             int* __restrict__ c32, int* __restrict__ map) {
    __shared__ int cnt[64];
    __shared__ int bse[64];
    int tid = threadIdx.x;
    if (tid < 64) cnt[tid] = 0;
    __syncthreads();
    int idx = blockIdx.x * 256 + tid;           // B*E
    int b = idx >> 14;
    int s = src[idx], d = dst[idx], t = et[idx];
    atomicAdd(&counts[(b * 2 + 0) * NN + s], 1);
    atomicAdd(&counts[(b * 2 + 1) * NN + d], 1);
    int bin0 = b * 16 + t;
    int bin1 = b * 16 + 8 + t;
    int k0 = (b << 16) | (t << 12) | d;          // dir-out msg: W[t] @ h[d]
    int k1 = (b << 16) | ((t + 8) << 12) | s;    // dir-in  msg: W[t+8] @ h[s]
    bool w0 = (atomicCAS(&map[k0], -1, -2) == -1);
    bool w1 = (atomicCAS(&map[k1], -1, -2) == -1);
    int r0 = w0 ? atomicAdd(&cnt[bin0], 1) : 0;
    int r1 = w1 ? atomicAdd(&cnt[bin1], 1) : 0;
    __syncthreads();
    if (tid < 64) bse[tid] = cnt[tid] ? atomicAdd(&c32[tid * 16], cnt[tid]) : 0;
    __syncthreads();
    if (w0) map[k0] = bse[bin0] + r0;
    if (w1) map[k1] = bse[bin1] + r1;
}

__global__ __launch_bounds__(1024) void scan_kernel(const int* __restrict__ counts,
                                                    int* __restrict__ offs,
                                                    int* __restrict__ cursor) {
    __shared__ int lsum[1024];
    int t = threadIdx.x, seg = blockIdx.x;      // 8 segments of 4096
    int4 v = ((const int4*)(counts + (size_t)seg * NN))[t];
    int s1 = v.x + v.y, s2 = s1 + v.z, s3 = s2 + v.w;
    lsum[t] = s3;
    __syncthreads();
    for (int off = 1; off < 1024; off <<= 1) {
        int tmp = (t >= off) ? lsum[t - off] : 0;
        __syncthreads();
        lsum[t] += tmp;
        __syncthreads();
    }
    int base = lsum[t] - s3;
    int* o = offs + (size_t)seg * OSTRIDE;
    o[4 * t] = base; o[4 * t + 1] = base + v.x; o[4 * t + 2] = base + s1; o[4 * t + 3] = base + s2;
    if (t == 1023) o[4096] = lsum[1023];
    int* c = cursor + (size_t)seg * NN;
    c[4 * t] = base; c[4 * t + 1] = base + v.x; c[4 * t + 2] = base + s1; c[4 * t + 3] = base + s2;
}

// type-major segments seg = b*16 + t16 (64 bins of unique counts), padded to 128;
// inits ttype=-1, zeroes idx2 pad rows.
__global__ void scan2_kernel(const int* __restrict__ c32, int* __restrict__ type_cursor,
                             int* __restrict__ tile_type, int* __restrict__ idx2) {
    __shared__ int pad[64];
    int t = threadIdx.x;                        // 0..63 = b*16 + t16
    for (int k = t; k < MAXTILES; k += 64) tile_type[k] = -1;
    __syncthreads();
    int cnt = c32[t * 16];
    int padded = ((cnt + 127) >> 7) << 7;
    pad[t] = padded;
    __syncthreads();
    int off = 0;
    for (int k = 0; k < t; ++k) off += pad[k];
    type_cursor[t] = off;
    int t16 = t & 15;
    int tile0 = off >> 7;
    for (int k = 0; k < (padded >> 7); ++k) tile_type[tile0 + k] = t16;
    for (int r = off + cnt; r < off + padded; ++r) idx2[r] = 0;
}

// per edge: look up dedup'd msg rows, write idx2 (dup-safe) + node-major entries
__global__ void fill3_kernel(const int* __restrict__ src, const int* __restrict__ dst,
                             const int* __restrict__ et, const int* __restrict__ type_cursor,
                             int* __restrict__ node_cursor, int* __restrict__ entries,
                             int* __restrict__ idx2, const int* __restrict__ map) {
    int idx = blockIdx.x * 256 + threadIdx.x;   // B*E
    int b = idx >> 14;
    int s = src[idx], d = dst[idx], t = et[idx];
    int k0 = (b << 16) | (t << 12) | d;
    int k1 = (b << 16) | ((t + 8) << 12) | s;
    int p0 = type_cursor[b * 16 + t] + map[k0];
    int p1 = type_cursor[b * 16 + t + 8] + map[k1];
    idx2[p0] = b * NN + d;
    idx2[p1] = b * NN + s;
    int q0 = atomicAdd(&node_cursor[(b * 2 + 0) * NN + s], 1);
    entries[(size_t)(b * 2 + 0) * EE + q0] = (p0 << 4) | t;
    int q1 = atomicAdd(&node_cursor[(b * 2 + 1) * NN + d], 1);
    entries[(size_t)(b * 2 + 1) * EE + q1] = (p1 << 4) | (t + 8);
}

// ============ GEMM cores ============
#define COMP_128x64(cb)                                                                 \
    _Pragma("unroll")                                                                   \
    for (int kk = 0; kk < 2; ++kk) {                                                    \
        short8 af[4], bfv[2];                                                           \
        _Pragma("unroll")                                                               \
        for (int m = 0; m < 4; ++m) {                                                   \
            int R = wr * 64 + m * 16 + lr;                                              \
            af[m] = *(const short8*)((const char*)As + (cb) * 16384 + R * 128 + (((kk * 4 + hi) ^ rx) << 4)); \
        }                                                                               \
        _Pragma("unroll")                                                               \
        for (int n = 0; n < 2; ++n) {                                                   \
            int R = wc * 32 + n * 16 + lr;                                              \
            bfv[n] = *(const short8*)((const char*)Bs + (cb) * 8192 + R * 128 + (((kk * 4 + hi) ^ rx) << 4)); \
        }                                                                               \
        _Pragma("unroll")                                                               \
        for (int m = 0; m < 4; ++m)                                                     \
            _Pragma("unroll")                                                           \
            for (int n = 0; n < 2; ++n)                                                 \
                acc[m][n] = __builtin_amdgcn_mfma_f32_16x16x32_bf16(bfv[n], af[m], acc[m][n], 0, 0, 0); \
    }

#define PIPE_WAIT(NSTR)                                                                 \
    asm volatile("s_waitcnt vmcnt(" NSTR ")" ::: "memory");                             \
    __builtin_amdgcn_s_barrier();                                                       \
    __builtin_amdgcn_sched_barrier(0);

// ---------------- message GEMM: msgs[p] = h_bf[idx2[p]] @ W[tile_type]^T ----------------
// N=256 per block: A-panel gathered ONCE, 64 MFMA/wave per K-wait. grid = MAXTILES,
// single-buffered LDS 48KB (A 16K + B 32K), K=256 -> 4 iterations.
__global__ __launch_bounds__(256) void gemm_msgs(const unsigned short* __restrict__ A,
                                                 const unsigned short* __restrict__ W2,
                                                 const int* __restrict__ idx2,
                                                 const int* __restrict__ tile_type,
                                                 unsigned short* __restrict__ C) {
    __shared__ __align__(16) unsigned short As[128 * 64];
    __shared__ __align__(16) unsigned short Bs[256 * 64];
    const int bid = blockIdx.x;
    const int by = (bid & 7) * (MAXTILES / 8) + (bid >> 3);   // XCD-chunked
    const int t16 = tile_type[by];
    if (t16 < 0) return;
    const int r0 = by << 7;
    const int tid = threadIdx.x;
    const int wv = tid >> 6, lane = tid & 63;
    const int wr = wv >> 1, wc = wv & 1;
    const int lr = lane & 15, hi = lane >> 4, rx = lane & 7;
    const int strow = tid >> 3;                 // 0..31
    const int scol = ((tid & 7) ^ ((tid >> 3) & 7)) << 3;
    int ar[4];
#pragma unroll
    for (int i = 0; i < 4; ++i) ar[i] = idx2[r0 + strow + i * 32];
    const unsigned short* Bg = W2 + (size_t)t16 * (DD * DD) + (size_t)strow * DD + scol;
    f32x4 acc[4][8] = {};
    for (int k0 = 0; k0 < DD; k0 += 64) {
#pragma unroll
        for (int i = 0; i < 4; ++i)
            __builtin_amdgcn_global_load_lds(
                (const AS1 void*)(A + (size_t)ar[i] * DD + scol + k0),
                (AS3 void*)((char*)As + wv * 1024 + i * 4096), 16, 0, 0);
#pragma unroll
        for (int i = 0; i < 8; ++i)
            __builtin_amdgcn_global_load_lds(
                (const AS1 void*)(Bg + (size_t)(i * 32) * DD + k0),
                (AS3 void*)((char*)Bs + wv * 1024 + i * 4096), 16, 0, 0);
        __syncthreads();
#pragma unroll
        for (int kk = 0; kk < 2; ++kk) {
            short8 af[4], bfv[8];
#pragma unroll
            for (int m = 0; m < 4; ++m) {
                int R = wr * 64 + m * 16 + lr;
                af[m] = *(const short8*)((const char*)As + R * 128 + (((kk * 4 + hi) ^ rx) << 4));
            }
#pragma unroll
            for (int n = 0; n < 8; ++n) {
                int R = wc * 128 + n * 16 + lr;
                bfv[n] = *(const short8*)((const char*)Bs + R * 128 + (((kk * 4 + hi) ^ rx) << 4));
            }
#pragma unroll
            for (int m = 0; m < 4; ++m)
#pragma unroll
                for (int n = 0; n < 8; ++n)
                    acc[m][n] = __builtin_amdgcn_mfma_f32_16x16x32_bf16(bfv[n], af[m], acc[m][n], 0, 0, 0);
        }
        __syncthreads();
    }
    const int erow = r0 + wr * 64 + lr;
    const int ecol = wc * 128 + (hi << 2);
#pragma unroll
    for (int m = 0; m < 4; ++m)
#pragma unroll
        for (int n = 0; n < 8; ++n) {
            ushort4 o;
            o.x = f2bf(acc[m][n][0]); o.y = f2bf(acc[m][n][1]);
            o.z = f2bf(acc[m][n][2]); o.w = f2bf(acc[m][n][3]);
            *(ushort4*)&C[(size_t)(erow + m * 16) * DD + ecol + n * 16] = o;
        }
}

// ---------------- RZU GEMM with fused GRU-gate epilogue (128x64, K=768 -> 12 tiles) ----------------
__global__ __launch_bounds__(256) void gemm_rzu(const unsigned short* __restrict__ A,
                                                const unsigned short* __restrict__ Bt,
                                                const float* __restrict__ br,
                                                const float* __restrict__ bz,
                                                const float* __restrict__ h,
                                                unsigned short* __restrict__ RH,
                                                unsigned short* __restrict__ Zb,
                                                unsigned short* __restrict__ Ub) {
    __shared__ __align__(16) unsigned short As[2 * 128 * 64];
    __shared__ __align__(16) unsigned short Bs[2 * 64 * 64];
    const int bid = blockIdx.x;
    const int wg = (bid & 7) * 192 + (bid >> 3);   // nwg=1536, XCD-chunked
    const int bx = wg % 12, by = wg / 12;
    const int r0 = by << 7, c0 = bx << 6;
    const int tid = threadIdx.x;
    const int wv = tid >> 6, lane = tid & 63;
    const int wr = wv >> 1, wc = wv & 1;
    const int lr = lane & 15, hi = lane >> 4, rx = lane & 7;
    const int strow = tid >> 3;
    const int scol = ((tid & 7) ^ ((tid >> 3) & 7)) << 3;
    const unsigned short* Ag = A + (size_t)(r0 + strow) * 768 + scol;
    const unsigned short* Bg = Bt + (size_t)(c0 + strow) * 768 + scol;
    f32x4 acc[4][2] = {};
#define RZ_STG(buf, kof)                                                                \
    { _Pragma("unroll")                                                                 \
      for (int i = 0; i < 4; ++i)                                                       \
          __builtin_amdgcn_global_load_lds(                                             \
              (const AS1 void*)(Ag + (size_t)(i * 32) * 768 + (kof)),                   \
              (AS3 void*)((char*)As + (buf) * 16384 + wv * 1024 + i * 4096), 16, 0, 0); \
      __builtin_amdgcn_global_load_lds(                                                 \
          (const AS1 void*)(Bg + (kof)),                                                \
          (AS3 void*)((char*)Bs + (buf) * 8192 + wv * 1024), 16, 0, 0);                 \
      __builtin_amdgcn_global_load_lds(                                                 \
          (const AS1 void*)(Bg + (size_t)32 * 768 + (kof)),                             \
          (AS3 void*)((char*)Bs + (buf) * 8192 + wv * 1024 + 4096), 16, 0, 0); }
    RZ_STG(0, 0)
    for (int it = 0; it < 11; ++it) {
        RZ_STG((it + 1) & 1, (it + 1) * 64)
        PIPE_WAIT("6")
        COMP_128x64(it & 1)
        __builtin_amdgcn_s_barrier();
    }
    PIPE_WAIT("0")
    COMP_128x64(1)
    const int erow = r0 + wr * 64 + lr;
    const int ecol = c0 + wc * 32 + (hi << 2);
    const int region = c0 >> 8;
#pragma unroll
    for (int m = 0; m < 4; ++m)
#pragma unroll
        for (int n = 0; n < 2; ++n) {
            int gr = erow + m * 16;
            int gc = ecol + n * 16;
            f32x4 v = acc[m][n];
            if (region == 0) {
                float4 bb = *(const float4*)&br[gc];
                float4 hv = *(const float4*)&h[(size_t)gr * 256 + gc];
                ushort4 o;
                o.x = f2bf(sigmoidf_(v[0] + bb.x) * hv.x);
                o.y = f2bf(sigmoidf_(v[1] + bb.y) * hv.y);
                o.z = f2bf(sigmoidf_(v[2] + bb.z) * hv.z);
                o.w = f2bf(sigmoidf_(v[3] + bb.w) * hv.w);
                *(ushort4*)&RH[(size_t)gr * 256 + gc] = o;
            } else if (region == 1) {
                int c = gc - 256;
                float4 bb = *(const float4*)&bz[c];
                ushort4 o;
                o.x = f2bf(sigmoidf_(v[0] + bb.x));
                o.y = f2bf(sigmoidf_(v[1] + bb.y));
                o.z = f2bf(sigmoidf_(v[2] + bb.z));
                o.w = f2bf(sigmoidf_(v[3] + bb.w));
                *(ushort4*)&Zb[(size_t)gr * 256 + c] = o;
            } else {
                int c = gc - 512;
                ushort4 o;
                o.x = f2bf(v[0]); o.y = f2bf(v[1]); o.z = f2bf(v[2]); o.w = f2bf(v[3]);
                *(ushort4*)&Ub[(size_t)gr * 256 + c] = o;
            }
        }
}

// ---------------- HH GEMM with fused h-update epilogue (64x64, K=256 -> 4 tiles) ----------------
__global__ __launch_bounds__(256) void gemm_hh(const unsigned short* __restrict__ A,
                                               const unsigned short* __restrict__ Bt,
                                               const unsigned short* __restrict__ Zb,
                                               const unsigned short* __restrict__ Ub,
                                               const float* __restrict__ bh,
                                               float* __restrict__ h,
                                               unsigned short* __restrict__ hbf,
                                               unsigned short* __restrict__ Xbf) {
    __shared__ __align__(16) unsigned short As[2 * 64 * 64];
    __shared__ __align__(16) unsigned short Bs[2 * 64 * 64];
    const int bid = blockIdx.x;
    const int wg = (bid & 7) * 128 + (bid >> 3);   // nwg=1024, XCD-chunked
    const int r0 = wg >> 2 << 6, c0 = (wg & 3) << 6;
    const int tid = threadIdx.x;
    const int wv = tid >> 6, lane = tid & 63;
    const int wr = wv >> 1, wc = wv & 1;
    const int lr = lane & 15, hi = lane >> 4, rx = lane & 7;
    const int srow = wv * 8 + (lane >> 3);
    const int scol = ((lane & 7) ^ (lane >> 3)) << 3;
    const unsigned short* Ag = A + (size_t)(r0 + srow) * 256 + scol;
    const unsigned short* Bg = Bt + (size_t)(c0 + srow) * 256 + scol;
    f32x4 acc[2][2] = {};
#define HH_STG(buf, kof)                                                                \
    { _Pragma("unroll")                                                                 \
      for (int i = 0; i < 2; ++i) {                                                     \
          __builtin_amdgcn_global_load_lds(                                             \
              (const AS1 void*)(Ag + (size_t)(i * 32) * 256 + (kof)),                   \
              (AS3 void*)((char*)As + (buf) * 8192 + wv * 1024 + i * 4096), 16, 0, 0);  \
          __builtin_amdgcn_global_load_lds(                                             \
              (const AS1 void*)(Bg + (size_t)(i * 32) * 256 + (kof)),                   \
              (AS3 void*)((char*)Bs + (buf) * 8192 + wv * 1024 + i * 4096), 16, 0, 0); } }
#define COMP_64x64(cb)                                                                  \
    _Pragma("unroll")                                                                   \
    for (int kk = 0; kk < 2; ++kk) {                                                    \
        short8 af[2], bfv[2];                                                           \
        _Pragma("unroll")                                                               \
        for (int m = 0; m < 2; ++m) {                                                   \
            int R = wr * 32 + m * 16 + lr;                                              \
            af[m] = *(const short8*)((const char*)As + (cb) * 8192 + R * 128 + (((kk * 4 + hi) ^ rx) << 4)); \
        }                                                                               \
        _Pragma("unroll")                                                               \
        for (int n = 0; n < 2; ++n) {                                                   \
            int R = wc * 32 + n * 16 + lr;                                              \
            bfv[n] = *(const short8*)((const char*)Bs + (cb) * 8192 + R * 128 + (((kk * 4 + hi) ^ rx) << 4)); \
        }                                                                               \
        _Pragma("unroll")                                                               \
        for (int m = 0; m < 2; ++m)                                                     \
            _Pragma("unroll")                                                           \
            for (int n = 0; n < 2; ++n)                                                 \
                acc[m][n] = __builtin_amdgcn_mfma_f32_16x16x32_bf16(bfv[n], af[m], acc[m][n], 0, 0, 0); \
    }
    HH_STG(0, 0)
    for (int it = 0; it < 3; ++it) {
        HH_STG((it + 1) & 1, (it + 1) * 64)
        PIPE_WAIT("4")
        COMP_64x64(it & 1)
        __builtin_amdgcn_s_barrier();
    }
    PIPE_WAIT("0")
    COMP_64x64(1)
    const int erow = r0 + wr * 32 + lr;
    const int ecol = c0 + wc * 32 + (hi << 2);
#pragma unroll
    for (int m = 0; m < 2; ++m)
#pragma unroll
        for (int n = 0; n < 2; ++n) {
            int gr = erow + m * 16;
            int gc = ecol + n * 16;
            size_t base = (size_t)gr * 256 + gc;
            f32x4 v = acc[m][n];
            float4 bb = *(const float4*)&bh[gc];
            float4 hv = *(const float4*)&h[base];
            ushort4 zp = *(const ushort4*)&Zb[base];
            ushort4 up = *(const ushort4*)&Ub[base];
            float4 hn;
            {
                float z = bf2f(zp.x); hn.x = (1.f - z) * hv.x + z * tanhf(bf2f(up.x) + v[0] + bb.x);
            }{
                float z = bf2f(zp.y); hn.y = (1.f - z) * hv.y + z * tanhf(bf2f(up.y) + v[1] + bb.y);
            }{
                float z = bf2f(zp.z); hn.z = (1.f - z) * hv.z + z * tanhf(bf2f(up.z) + v[2] + bb.z);
            }{
                float z = bf2f(zp.w); hn.w = (1.f - z) * hv.w + z * tanhf(bf2f(up.w) + v[3] + bb.w);
            }
            *(float4*)&h[base] = hn;
            ushort4 o;
            o.x = f2bf(hn.x); o.y = f2bf(hn.y); o.z = f2bf(hn.z); o.w = f2bf(hn.w);
            *(ushort4*)&hbf[base] = o;
            *(ushort4*)&Xbf[(size_t)gr * 768 + 512 + gc] = o;
        }
}

// ---------------- CSR gather: sum message rows per (b,dir,node), bf16 out ----------------
__global__ void gather2_kernel(const unsigned short* __restrict__ msgs,
                               const int* __restrict__ offs, const int* __restrict__ entries,
                               const float* __restrict__ bias, unsigned short* __restrict__ Xb) {
    int wv = threadIdx.x >> 6, lane = threadIdx.x & 63;
    int slot = blockIdx.x * 4 + wv;             // [0, B*2*N)
    int b = slot >> 13;
    int dir = (slot >> 12) & 1;
    int node = slot & 4095;
    const int* o = offs + (size_t)(b * 2 + dir) * OSTRIDE;
    int beg = o[node], end = o[node + 1];
    const int* ent = entries + (size_t)(b * 2 + dir) * EE;
    const float4* bias4 = (const float4*)bias;
    float4 acc = {0.f, 0.f, 0.f, 0.f};
    for (int p = beg; p < end; ++p) {
        int e2 = ent[p];
        int row = e2 >> 4, t = e2 & 15;
        ushort4 pv = *(const ushort4*)(msgs + (size_t)row * DD + lane * 4);
        float4 bv = bias4[t * 64 + lane];
        acc.x += bf2f(pv.x) + bv.x;
        acc.y += bf2f(pv.y) + bv.y;
        acc.z += bf2f(pv.z) + bv.z;
        acc.w += bf2f(pv.w) + bv.w;
    }
    ushort4 o4;
    o4.x = f2bf(acc.x); o4.y = f2bf(acc.y); o4.z = f2bf(acc.z); o4.w = f2bf(acc.w);
    int colbase = (dir == 0 ? 256 : 0) + lane * 4;
    *(ushort4*)(Xb + ((size_t)b * NN + node) * 768 + colbase) = o4;
}

// ---------------- final attention readout ----------------
__global__ void final_reduce(const float* __restrict__ h, const float* __restrict__ ann,
                             const float* __restrict__ Wa, const float* __restrict__ ba,
                             const float* __restrict__ Wo, const float* __restrict__ bo,
                             float* __restrict__ acc) {
    int wv = threadIdx.x >> 6, lane = threadIdx.x & 63;
    int b = blockIdx.x >> 5;
    int nbase = (blockIdx.x & 31) * 128 + wv * 32;
    float4 wah = ((const float4*)Wa)[lane];
    float4 woh = ((const float4*)Wo)[lane];
    float4 waa = {0, 0, 0, 0}, woa = {0, 0, 0, 0};
    if (lane < 16) {
        waa = ((const float4*)(Wa + 256))[lane];
        woa = ((const float4*)(Wo + 256))[lane];
    }
    float bav = ba[0], bov = bo[0];
    float part = 0.f;
    for (int it = 0; it < 32; ++it) {
        int node = nbase + it;
        float4 hv = ((const float4*)(h + ((size_t)b * NN + node) * DD))[lane];
        float sa = hv.x * wah.x + hv.y * wah.y + hv.z * wah.z + hv.w * wah.w;
        float so = hv.x * woh.x + hv.y * woh.y + hv.z * woh.z + hv.w * woh.w;
        if (lane < 16) {
            float4 av = ((const float4*)(ann + ((size_t)b * NN + node) * ADIM))[lane];
            sa += av.x * waa.x + av.y * waa.y + av.z * waa.z + av.w * waa.w;
            so += av.x * woa.x + av.y * woa.y + av.z * woa.z + av.w * woa.w;
        }
        for (int off = 32; off; off >>= 1) {
            sa += __shfl_down(sa, off);
            so += __shfl_down(so, off);
        }
        if (lane == 0) part += sigmoidf_(sa + bav) * tanhf(so + bov);
    }
    if (lane == 0) atomicAdd(&acc[b], part);
}

__global__ void final_out(const float* __restrict__ acc, float* __restrict__ out) {
    int b = threadIdx.x;
    if (b < BB) out[b] = sigmoidf_(acc[b]);
}

extern "C" void kernel_launch(void* const* d_in, const int* in_sizes, int n_in,
                              void* d_out, int out_size, void* d_ws, size_t ws_size,
                              hipStream_t stream) {
    const int*   ann_id     = (const int*)d_in[0];
    const int*   src        = (const int*)d_in[1];
    const int*   dst        = (const int*)d_in[2];
    const int*   etype      = (const int*)d_in[3];
    const float* edge_embed = (const float*)d_in[4];
    const float* edge_bias  = (const float*)d_in[5];
    const float* type_embed = (const float*)d_in[6];
    const float* Wr = (const float*)d_in[7];
    const float* br = (const float*)d_in[8];
    const float* Wz = (const float*)d_in[9];
    const float* bz = (const float*)d_in[10];
    const float* Wh = (const float*)d_in[11];
    const float* bh = (const float*)d_in[12];
    const float* Wa = (const float*)d_in[13];
    const float* ba = (const float*)d_in[14];
    const float* Wo = (const float*)d_in[15];
    const float* bo = (const float*)d_in[16];
    float* out = (float*)d_out;

    char* base = (char*)d_ws;
    size_t off = 0;
    auto alloc = [&](size_t bytes) { char* p = base + off; off += (bytes + 255) & ~(size_t)255; return p; };
    float* ann  = (float*)alloc((size_t)BB * NN * ADIM * 4);          // 4 MB
    float* h    = (float*)alloc((size_t)BB * NN * DD * 4);            // 16 MB
    float* acc  = (float*)alloc(64);
    unsigned short* h_bf   = (unsigned short*)alloc((size_t)BB * NN * DD * 2);   // 8 MB
    unsigned short* W2bf   = (unsigned short*)alloc((size_t)TT * DD * DD * 2);   // 2 MB
    unsigned short* Wcatbf = (unsigned short*)alloc(768 * 768 * 2);
    unsigned short* Whhbf  = (unsigned short*)alloc(256 * 256 * 2);
    unsigned short* msgs   = (unsigned short*)alloc((size_t)MAXM * DD * 2);      // 71 MB
    unsigned short* Xbf    = (unsigned short*)alloc((size_t)BB * NN * 768 * 2);  // 24 MB
    unsigned short* RHbf   = (unsigned short*)alloc((size_t)BB * NN * DD * 2);   // 8 MB
    unsigned short* Zb     = (unsigned short*)alloc((size_t)BB * NN * DD * 2);   // 8 MB
    unsigned short* Ub     = (unsigned short*)alloc((size_t)BB * NN * DD * 2);   // 8 MB
    int* counts  = (int*)alloc((size_t)BB * 2 * NN * 4);              // 128 KB
    int* c32     = (int*)alloc(1024 * 4);                             // 64 bins x 16 ints
    int* cursor  = (int*)alloc((size_t)BB * 2 * NN * 4);
    int* offsets = (int*)alloc((size_t)BB * 2 * OSTRIDE * 4);
    int* entries = (int*)alloc((size_t)BB * 2 * EE * 4);              // 512 KB
    int* tcur    = (int*)alloc(64 * 4);
    int* ttype   = (int*)alloc(MAXTILES * 4);
    int* idx2    = (int*)alloc((size_t)MAXM * 4);                     // 557 KB
    int* map     = (int*)alloc((size_t)262144 * 4);                   // 1 MB
    // total ~153 MB

    // ---- prep (once per call) ----
    prep_kernel<<<dim3(7680), dim3(256), 0, stream>>>(
        ann_id, type_embed, edge_embed, Wr, Wz, Wh,
        ann, h, h_bf, Xbf, W2bf, Wcatbf, Whhbf, acc, counts, c32, map);
    claim_kernel<<<dim3((BB * EE) / 256), dim3(256), 0, stream>>>(
        src, dst, etype, counts, c32, map);
    scan_kernel<<<dim3(BB * 2), dim3(1024), 0, stream>>>(counts, offsets, cursor);
    scan2_kernel<<<dim3(1), dim3(64), 0, stream>>>(c32, tcur, ttype, idx2);
    fill3_kernel<<<dim3((BB * EE) / 256), dim3(256), 0, stream>>>(
        src, dst, etype, tcur, cursor, entries, idx2, map);

    for (int s = 0; s < STEPS; ++s) {
        gemm_msgs<<<dim3(MAXTILES), dim3(256), 0, stream>>>(
            h_bf, W2bf, idx2, ttype, msgs);
        gather2_kernel<<<dim3(BB * 2 * NN / 4), dim3(256), 0, stream>>>(
            msgs, offsets, entries, edge_bias, Xbf);
        gemm_rzu<<<dim3(1536), dim3(256), 0, stream>>>(
            Xbf, Wcatbf, br, bz, h, RHbf, Zb, Ub);
        gemm_hh<<<dim3(1024), dim3(256), 0, stream>>>(
            RHbf, Whhbf, Zb, Ub, bh, h, h_bf, Xbf);
    }

    final_reduce<<<dim3(128), dim3(256), 0, stream>>>(h, ann, Wa, ba, Wo, bo, acc);
    final_out<<<dim3(1), dim3(64), 0, stream>>>(acc, out);
}

// Round 18
// 411.439 us; speedup vs baseline: 1.1465x; 1.1465x over previous
//
#include <hip/hip_runtime.h>
#include <cstdint>

#define BB 4
#define NN 4096
#define EE 16384
#define DD 256
#define ADIM 64
#define TT 16
#define HALFE 8
#define STEPS 3
#define OSTRIDE 4160
#define MAXTILES 1088            // 128-row msg tiles (uniques <= 139264 padded worst case)
#define MAXM (MAXTILES * 128)

#define AS1 __attribute__((address_space(1)))
#define AS3 __attribute__((address_space(3)))

typedef __attribute__((ext_vector_type(8))) short short8;
typedef __attribute__((ext_vector_type(4))) float f32x4;

__device__ __forceinline__ float sigmoidf_(float x) { return 1.0f / (1.0f + __expf(-x)); }

__device__ __forceinline__ unsigned short f2bf(float x) {
    unsigned u = __float_as_uint(x);
    u += 0x7fffu + ((u >> 16) & 1u);
    return (unsigned short)(u >> 16);
}
__device__ __forceinline__ float bf2f(unsigned short b) {
    return __uint_as_float(((unsigned)b) << 16);
}

// ---------------- fused prep: init + conv(W2) + wcat + whh + zero(acc,counts,c32,map) ----------------
__global__ void prep_kernel(const int* __restrict__ ann_id, const float* __restrict__ type_embed,
                            const float* __restrict__ edge_embed, const float* __restrict__ Wr,
                            const float* __restrict__ Wz, const float* __restrict__ Wh,
                            float* __restrict__ ann, float* __restrict__ h,
                            unsigned short* __restrict__ hbf, unsigned short* __restrict__ Xbf,
                            unsigned short* __restrict__ W2bf, unsigned short* __restrict__ Wcatbf,
                            unsigned short* __restrict__ Whhbf, float* __restrict__ acc,
                            int* __restrict__ counts, int* __restrict__ c32,
                            int* __restrict__ map) {
    int bid = blockIdx.x, tid = threadIdx.x;
    if (bid < 4096) {                           // init: B*N*64 threads, 4 elems each
        if (bid < 128) counts[bid * 256 + tid] = 0;
        if (bid < 1024) map[bid * 256 + tid] = -1;
        if (bid == 0) { c32[tid] = 0; c32[256 + tid] = 0; c32[512 + tid] = 0; c32[768 + tid] = 0; }
        if (bid == 0 && tid < 16) acc[tid] = 0.f;
        int idx = bid * 256 + tid;
        int bn = idx >> 6, q = idx & 63;
        int id = ann_id[bn];
        float4 v = {0.f, 0.f, 0.f, 0.f};
        if (q < 16) {
            if (id > 0) v = ((const float4*)(type_embed + (size_t)(id - 1) * ADIM))[q];
            ((float4*)(ann + (size_t)bn * ADIM))[q] = v;
        }
        ((float4*)(h + (size_t)bn * DD))[q] = v;
        ushort4 o;
        o.x = f2bf(v.x); o.y = f2bf(v.y); o.z = f2bf(v.z); o.w = f2bf(v.w);
        ((ushort4*)(hbf + (size_t)bn * DD))[q] = o;
        ((ushort4*)(Xbf + (size_t)bn * 768 + 512))[q] = o;
    } else if (bid < 5120) {                    // conv edge_embed -> W2bf, 4 elems each
        int idx = (bid - 4096) * 256 + tid;
        float4 v = ((const float4*)edge_embed)[idx];
        ushort4 o;
        o.x = f2bf(v.x); o.y = f2bf(v.y); o.z = f2bf(v.z); o.w = f2bf(v.w);
        ((ushort4*)W2bf)[idx] = o;
    } else if (bid < 7424) {                    // Wcat_t[c][k]
        int idx = (bid - 5120) * 256 + tid;     // 768*768
        int c = idx / 768, k = idx % 768;
        float v;
        if (c < 256)       v = Wr[c * 768 + k];
        else if (c < 512)  v = Wz[(c - 256) * 768 + k];
        else               v = (k < 512) ? Wh[(c - 512) * 768 + k] : 0.f;
        Wcatbf[idx] = f2bf(v);
    } else {                                    // Whh_t[i][k] = Wh[i][512+k]
        int idx = (bid - 7424) * 256 + tid;     // 256*256
        int i = idx / 256, k = idx % 256;
        Whhbf[idx] = f2bf(Wh[i * 768 + 512 + k]);
    }
}

// ---------------- claim: node-degree counts + dedup-claim unique (b,t16,nbr) keys ----------------
__global__ void claim_kernel(const int* __restrict__ src, const int* __restrict__ dst,
                             const int* __restrict__ et, int* __restrict__ counts,
                             int* __restrict__ c32, int* __restrict__ map) {
    __shared__ int cnt[64];
    __shared__ int bse[64];
    int tid = threadIdx.x;
    if (tid < 64) cnt[tid] = 0;
    __syncthreads();
    int idx = blockIdx.x * 256 + tid;           // B*E
    int b = idx >> 14;
    int s = src[idx], d = dst[idx], t = et[idx];
    atomicAdd(&counts[(b * 2 + 0) * NN + s], 1);
    atomicAdd(&counts[(b * 2 + 1) * NN + d], 1);
    int bin0 = b * 16 + t;
    int bin1 = b * 16 + 8 + t;
    int k0 = (b << 16) | (t << 12) | d;          // dir-out msg: W[t] @ h[d]
    int k1 = (b << 16) | ((t + 8) << 12) | s;    // dir-in  msg: W[t+8] @ h[s]
    bool w0 = (atomicCAS(&map[k0], -1, -2) == -1);
    bool w1 = (atomicCAS(&map[k1], -1, -2) == -1);
    int r0 = w0 ? atomicAdd(&cnt[bin0], 1) : 0;
    int r1 = w1 ? atomicAdd(&cnt[bin1], 1) : 0;
    __syncthreads();
    if (tid < 64) bse[tid] = cnt[tid] ? atomicAdd(&c32[tid * 16], cnt[tid]) : 0;
    __syncthreads();
    if (w0) map[k0] = bse[bin0] + r0;
    if (w1) map[k1] = bse[bin1] + r1;
}

__global__ __launch_bounds__(1024) void scan_kernel(const int* __restrict__ counts,
                                                    int* __restrict__ offs,
                                                    int* __restrict__ cursor) {
    __shared__ int lsum[1024];
    int t = threadIdx.x, seg = blockIdx.x;      // 8 segments of 4096
    int4 v = ((const int4*)(counts + (size_t)seg * NN))[t];
    int s1 = v.x + v.y, s2 = s1 + v.z, s3 = s2 + v.w;
    lsum[t] = s3;
    __syncthreads();
    for (int off = 1; off < 1024; off <<= 1) {
        int tmp = (t >= off) ? lsum[t - off] : 0;
        __syncthreads();
        lsum[t] += tmp;
        __syncthreads();
    }
    int base = lsum[t] - s3;
    int* o = offs + (size_t)seg * OSTRIDE;
    o[4 * t] = base; o[4 * t + 1] = base + v.x; o[4 * t + 2] = base + s1; o[4 * t + 3] = base + s2;
    if (t == 1023) o[4096] = lsum[1023];
    int* c = cursor + (size_t)seg * NN;
    c[4 * t] = base; c[4 * t + 1] = base + v.x; c[4 * t + 2] = base + s1; c[4 * t + 3] = base + s2;
}

// type-major segments seg = b*16 + t16 (64 bins of unique counts), padded to 128;
// inits ttype=-1, zeroes idx2 pad rows.
__global__ void scan2_kernel(const int* __restrict__ c32, int* __restrict__ type_cursor,
                             int* __restrict__ tile_type, int* __restrict__ idx2) {
    __shared__ int pad[64];
    int t = threadIdx.x;                        // 0..63 = b*16 + t16
    for (int k = t; k < MAXTILES; k += 64) tile_type[k] = -1;
    __syncthreads();
    int cnt = c32[t * 16];
    int padded = ((cnt + 127) >> 7) << 7;
    pad[t] = padded;
    __syncthreads();
    int off = 0;
    for (int k = 0; k < t; ++k) off += pad[k];
    type_cursor[t] = off;
    int t16 = t & 15;
    int tile0 = off >> 7;
    for (int k = 0; k < (padded >> 7); ++k) tile_type[tile0 + k] = t16;
    for (int r = off + cnt; r < off + padded; ++r) idx2[r] = 0;
}

// per edge: look up dedup'd msg rows, write idx2 (dup-safe) + node-major entries
__global__ void fill3_kernel(const int* __restrict__ src, const int* __restrict__ dst,
                             const int* __restrict__ et, const int* __restrict__ type_cursor,
                             int* __restrict__ node_cursor, int* __restrict__ entries,
                             int* __restrict__ idx2, const int* __restrict__ map) {
    int idx = blockIdx.x * 256 + threadIdx.x;   // B*E
    int b = idx >> 14;
    int s = src[idx], d = dst[idx], t = et[idx];
    int k0 = (b << 16) | (t << 12) | d;
    int k1 = (b << 16) | ((t + 8) << 12) | s;
    int p0 = type_cursor[b * 16 + t] + map[k0];
    int p1 = type_cursor[b * 16 + t + 8] + map[k1];
    idx2[p0] = b * NN + d;
    idx2[p1] = b * NN + s;
    int q0 = atomicAdd(&node_cursor[(b * 2 + 0) * NN + s], 1);
    entries[(size_t)(b * 2 + 0) * EE + q0] = (p0 << 4) | t;
    int q1 = atomicAdd(&node_cursor[(b * 2 + 1) * NN + d], 1);
    entries[(size_t)(b * 2 + 1) * EE + q1] = (p1 << 4) | (t + 8);
}

// ============ counted-vmcnt 2-phase GEMM cores (R12 config: 4 waves, 128x64 / 64x64) ============
#define COMP_128x64(cb)                                                                 \
    _Pragma("unroll")                                                                   \
    for (int kk = 0; kk < 2; ++kk) {                                                    \
        short8 af[4], bfv[2];                                                           \
        _Pragma("unroll")                                                               \
        for (int m = 0; m < 4; ++m) {                                                   \
            int R = wr * 64 + m * 16 + lr;                                              \
            af[m] = *(const short8*)((const char*)As + (cb) * 16384 + R * 128 + (((kk * 4 + hi) ^ rx) << 4)); \
        }                                                                               \
        _Pragma("unroll")                                                               \
        for (int n = 0; n < 2; ++n) {                                                   \
            int R = wc * 32 + n * 16 + lr;                                              \
            bfv[n] = *(const short8*)((const char*)Bs + (cb) * 8192 + R * 128 + (((kk * 4 + hi) ^ rx) << 4)); \
        }                                                                               \
        _Pragma("unroll")                                                               \
        for (int m = 0; m < 4; ++m)                                                     \
            _Pragma("unroll")                                                           \
            for (int n = 0; n < 2; ++n)                                                 \
                acc[m][n] = __builtin_amdgcn_mfma_f32_16x16x32_bf16(bfv[n], af[m], acc[m][n], 0, 0, 0); \
    }

#define PIPE_WAIT(NSTR)                                                                 \
    asm volatile("s_waitcnt vmcnt(" NSTR ")" ::: "memory");                             \
    __builtin_amdgcn_s_barrier();                                                       \
    __builtin_amdgcn_sched_barrier(0);

// ---------------- message GEMM: msgs[p] = h_bf[idx2[p]] @ W[tile_type]^T ----------------
// grid = MAXTILES*4 (128x64 tiles), K=256 -> 4 tiles, 6 loads/tile
__global__ __launch_bounds__(256) void gemm_msgs(const unsigned short* __restrict__ A,
                                                 const unsigned short* __restrict__ W2,
                                                 const int* __restrict__ idx2,
                                                 const int* __restrict__ tile_type,
                                                 unsigned short* __restrict__ C) {
    __shared__ __align__(16) unsigned short As[2 * 128 * 64];
    __shared__ __align__(16) unsigned short Bs[2 * 64 * 64];
    const int bid = blockIdx.x;
    const int wg = (bid & 7) * (MAXTILES * 4 / 8) + (bid >> 3);   // XCD-chunked
    const int by = wg >> 2, bx = wg & 3;
    const int t16 = tile_type[by];
    if (t16 < 0) return;
    const int r0 = by << 7, c0 = bx << 6;
    const int tid = threadIdx.x;
    const int wv = tid >> 6, lane = tid & 63;
    const int wr = wv >> 1, wc = wv & 1;
    const int lr = lane & 15, hi = lane >> 4, rx = lane & 7;
    const int strow = tid >> 3;                 // stage row 0..31 (wv*8 + lane>>3)
    const int scol = ((tid & 7) ^ ((tid >> 3) & 7)) << 3;
    int ar[4];
#pragma unroll
    for (int i = 0; i < 4; ++i) ar[i] = idx2[r0 + strow + i * 32];
    const unsigned short* Bg = W2 + (size_t)t16 * (DD * DD) + (size_t)(c0 + strow) * DD + scol;
    f32x4 acc[4][2] = {};
#define MS_STG(buf, kof)                                                                \
    { _Pragma("unroll")                                                                 \
      for (int i = 0; i < 4; ++i)                                                       \
          __builtin_amdgcn_global_load_lds(                                             \
              (const AS1 void*)(A + (size_t)ar[i] * DD + scol + (kof)),                 \
              (AS3 void*)((char*)As + (buf) * 16384 + wv * 1024 + i * 4096), 16, 0, 0); \
      __builtin_amdgcn_global_load_lds(                                                 \
          (const AS1 void*)(Bg + (kof)),                                                \
          (AS3 void*)((char*)Bs + (buf) * 8192 + wv * 1024), 16, 0, 0);                 \
      __builtin_amdgcn_global_load_lds(                                                 \
          (const AS1 void*)(Bg + (size_t)32 * DD + (kof)),                              \
          (AS3 void*)((char*)Bs + (buf) * 8192 + wv * 1024 + 4096), 16, 0, 0); }
    MS_STG(0, 0)
    for (int it = 0; it < 3; ++it) {
        MS_STG((it + 1) & 1, (it + 1) * 64)
        PIPE_WAIT("6")
        COMP_128x64(it & 1)
        __builtin_amdgcn_s_barrier();
    }
    PIPE_WAIT("0")
    COMP_128x64(1)
    const int erow = r0 + wr * 64 + lr;
    const int ecol = c0 + wc * 32 + (hi << 2);
#pragma unroll
    for (int m = 0; m < 4; ++m)
#pragma unroll
        for (int n = 0; n < 2; ++n) {
            ushort4 o;
            o.x = f2bf(acc[m][n][0]); o.y = f2bf(acc[m][n][1]);
            o.z = f2bf(acc[m][n][2]); o.w = f2bf(acc[m][n][3]);
            *(ushort4*)&C[(size_t)(erow + m * 16) * DD + ecol + n * 16] = o;
        }
}

// ---------------- RZU GEMM with fused GRU-gate epilogue (128x64, K=768 -> 12 tiles) ----------------
__global__ __launch_bounds__(256) void gemm_rzu(const unsigned short* __restrict__ A,
                                                const unsigned short* __restrict__ Bt,
                                                const float* __restrict__ br,
                                                const float* __restrict__ bz,
                                                const float* __restrict__ h,
                                                unsigned short* __restrict__ RH,
                                                unsigned short* __restrict__ Zb,
                                                unsigned short* __restrict__ Ub) {
    __shared__ __align__(16) unsigned short As[2 * 128 * 64];
    __shared__ __align__(16) unsigned short Bs[2 * 64 * 64];
    const int bid = blockIdx.x;
    const int wg = (bid & 7) * 192 + (bid >> 3);   // nwg=1536, XCD-chunked
    const int bx = wg % 12, by = wg / 12;
    const int r0 = by << 7, c0 = bx << 6;
    const int tid = threadIdx.x;
    const int wv = tid >> 6, lane = tid & 63;
    const int wr = wv >> 1, wc = wv & 1;
    const int lr = lane & 15, hi = lane >> 4, rx = lane & 7;
    const int strow = tid >> 3;
    const int scol = ((tid & 7) ^ ((tid >> 3) & 7)) << 3;
    const unsigned short* Ag = A + (size_t)(r0 + strow) * 768 + scol;
    const unsigned short* Bg = Bt + (size_t)(c0 + strow) * 768 + scol;
    f32x4 acc[4][2] = {};
#define RZ_STG(buf, kof)                                                                \
    { _Pragma("unroll")                                                                 \
      for (int i = 0; i < 4; ++i)                                                       \
          __builtin_amdgcn_global_load_lds(                                             \
              (const AS1 void*)(Ag + (size_t)(i * 32) * 768 + (kof)),                   \
              (AS3 void*)((char*)As + (buf) * 16384 + wv * 1024 + i * 4096), 16, 0, 0); \
      __builtin_amdgcn_global_load_lds(                                                 \
          (const AS1 void*)(Bg + (kof)),                                                \
          (AS3 void*)((char*)Bs + (buf) * 8192 + wv * 1024), 16, 0, 0);                 \
      __builtin_amdgcn_global_load_lds(                                                 \
          (const AS1 void*)(Bg + (size_t)32 * 768 + (kof)),                             \
          (AS3 void*)((char*)Bs + (buf) * 8192 + wv * 1024 + 4096), 16, 0, 0); }
    RZ_STG(0, 0)
    for (int it = 0; it < 11; ++it) {
        RZ_STG((it + 1) & 1, (it + 1) * 64)
        PIPE_WAIT("6")
        COMP_128x64(it & 1)
        __builtin_amdgcn_s_barrier();
    }
    PIPE_WAIT("0")
    COMP_128x64(1)
    const int erow = r0 + wr * 64 + lr;
    const int ecol = c0 + wc * 32 + (hi << 2);
    const int region = c0 >> 8;
#pragma unroll
    for (int m = 0; m < 4; ++m)
#pragma unroll
        for (int n = 0; n < 2; ++n) {
            int gr = erow + m * 16;
            int gc = ecol + n * 16;
            f32x4 v = acc[m][n];
            if (region == 0) {
                float4 bb = *(const float4*)&br[gc];
                float4 hv = *(const float4*)&h[(size_t)gr * 256 + gc];
                ushort4 o;
                o.x = f2bf(sigmoidf_(v[0] + bb.x) * hv.x);
                o.y = f2bf(sigmoidf_(v[1] + bb.y) * hv.y);
                o.z = f2bf(sigmoidf_(v[2] + bb.z) * hv.z);
                o.w = f2bf(sigmoidf_(v[3] + bb.w) * hv.w);
                *(ushort4*)&RH[(size_t)gr * 256 + gc] = o;
            } else if (region == 1) {
                int c = gc - 256;
                float4 bb = *(const float4*)&bz[c];
                ushort4 o;
                o.x = f2bf(sigmoidf_(v[0] + bb.x));
                o.y = f2bf(sigmoidf_(v[1] + bb.y));
                o.z = f2bf(sigmoidf_(v[2] + bb.z));
                o.w = f2bf(sigmoidf_(v[3] + bb.w));
                *(ushort4*)&Zb[(size_t)gr * 256 + c] = o;
            } else {
                int c = gc - 512;
                ushort4 o;
                o.x = f2bf(v[0]); o.y = f2bf(v[1]); o.z = f2bf(v[2]); o.w = f2bf(v[3]);
                *(ushort4*)&Ub[(size_t)gr * 256 + c] = o;
            }
        }
}

// ---------------- HH GEMM with fused h-update epilogue (64x64, K=256 -> 4 tiles) ----------------
__global__ __launch_bounds__(256) void gemm_hh(const unsigned short* __restrict__ A,
                                               const unsigned short* __restrict__ Bt,
                                               const unsigned short* __restrict__ Zb,
                                               const unsigned short* __restrict__ Ub,
                                               const float* __restrict__ bh,
                                               float* __restrict__ h,
                                               unsigned short* __restrict__ hbf,
                                               unsigned short* __restrict__ Xbf) {
    __shared__ __align__(16) unsigned short As[2 * 64 * 64];
    __shared__ __align__(16) unsigned short Bs[2 * 64 * 64];
    const int bid = blockIdx.x;
    const int wg = (bid & 7) * 128 + (bid >> 3);   // nwg=1024, XCD-chunked
    const int r0 = wg >> 2 << 6, c0 = (wg & 3) << 6;
    const int tid = threadIdx.x;
    const int wv = tid >> 6, lane = tid & 63;
    const int wr = wv >> 1, wc = wv & 1;
    const int lr = lane & 15, hi = lane >> 4, rx = lane & 7;
    const int srow = wv * 8 + (lane >> 3);
    const int scol = ((lane & 7) ^ (lane >> 3)) << 3;
    const unsigned short* Ag = A + (size_t)(r0 + srow) * 256 + scol;
    const unsigned short* Bg = Bt + (size_t)(c0 + srow) * 256 + scol;
    f32x4 acc[2][2] = {};
#define HH_STG(buf, kof)                                                                \
    { _Pragma("unroll")                                                                 \
      for (int i = 0; i < 2; ++i) {                                                     \
          __builtin_amdgcn_global_load_lds(                                             \
              (const AS1 void*)(Ag + (size_t)(i * 32) * 256 + (kof)),                   \
              (AS3 void*)((char*)As + (buf) * 8192 + wv * 1024 + i * 4096), 16, 0, 0);  \
          __builtin_amdgcn_global_load_lds(                                             \
              (const AS1 void*)(Bg + (size_t)(i * 32) * 256 + (kof)),                   \
              (AS3 void*)((char*)Bs + (buf) * 8192 + wv * 1024 + i * 4096), 16, 0, 0); } }
#define COMP_64x64(cb)                                                                  \
    _Pragma("unroll")                                                                   \
    for (int kk = 0; kk < 2; ++kk) {                                                    \
        short8 af[2], bfv[2];                                                           \
        _Pragma("unroll")                                                               \
        for (int m = 0; m < 2; ++m) {                                                   \
            int R = wr * 32 + m * 16 + lr;                                              \
            af[m] = *(const short8*)((const char*)As + (cb) * 8192 + R * 128 + (((kk * 4 + hi) ^ rx) << 4)); \
        }                                                                               \
        _Pragma("unroll")                                                               \
        for (int n = 0; n < 2; ++n) {                                                   \
            int R = wc * 32 + n * 16 + lr;                                              \
            bfv[n] = *(const short8*)((const char*)Bs + (cb) * 8192 + R * 128 + (((kk * 4 + hi) ^ rx) << 4)); \
        }                                                                               \
        _Pragma("unroll")                                                               \
        for (int m = 0; m < 2; ++m)                                                     \
            _Pragma("unroll")                                                           \
            for (int n = 0; n < 2; ++n)                                                 \
                acc[m][n] = __builtin_amdgcn_mfma_f32_16x16x32_bf16(bfv[n], af[m], acc[m][n], 0, 0, 0); \
    }
    HH_STG(0, 0)
    for (int it = 0; it < 3; ++it) {
        HH_STG((it + 1) & 1, (it + 1) * 64)
        PIPE_WAIT("4")
        COMP_64x64(it & 1)
        __builtin_amdgcn_s_barrier();
    }
    PIPE_WAIT("0")
    COMP_64x64(1)
    const int erow = r0 + wr * 32 + lr;
    const int ecol = c0 + wc * 32 + (hi << 2);
#pragma unroll
    for (int m = 0; m < 2; ++m)
#pragma unroll
        for (int n = 0; n < 2; ++n) {
            int gr = erow + m * 16;
            int gc = ecol + n * 16;
            size_t base = (size_t)gr * 256 + gc;
            f32x4 v = acc[m][n];
            float4 bb = *(const float4*)&bh[gc];
            float4 hv = *(const float4*)&h[base];
            ushort4 zp = *(const ushort4*)&Zb[base];
            ushort4 up = *(const ushort4*)&Ub[base];
            float4 hn;
            {
                float z = bf2f(zp.x); hn.x = (1.f - z) * hv.x + z * tanhf(bf2f(up.x) + v[0] + bb.x);
            }{
                float z = bf2f(zp.y); hn.y = (1.f - z) * hv.y + z * tanhf(bf2f(up.y) + v[1] + bb.y);
            }{
                float z = bf2f(zp.z); hn.z = (1.f - z) * hv.z + z * tanhf(bf2f(up.z) + v[2] + bb.z);
            }{
                float z = bf2f(zp.w); hn.w = (1.f - z) * hv.w + z * tanhf(bf2f(up.w) + v[3] + bb.w);
            }
            *(float4*)&h[base] = hn;
            ushort4 o;
            o.x = f2bf(hn.x); o.y = f2bf(hn.y); o.z = f2bf(hn.z); o.w = f2bf(hn.w);
            *(ushort4*)&hbf[base] = o;
            *(ushort4*)&Xbf[(size_t)gr * 768 + 512 + gc] = o;
        }
}

// ---------------- CSR gather: sum message rows per (b,dir,node), bf16 out ----------------
__global__ void gather2_kernel(const unsigned short* __restrict__ msgs,
                               const int* __restrict__ offs, const int* __restrict__ entries,
                               const float* __restrict__ bias, unsigned short* __restrict__ Xb) {
    int wv = threadIdx.x >> 6, lane = threadIdx.x & 63;
    int slot = blockIdx.x * 4 + wv;             // [0, B*2*N)
    int b = slot >> 13;
    int dir = (slot >> 12) & 1;
    int node = slot & 4095;
    const int* o = offs + (size_t)(b * 2 + dir) * OSTRIDE;
    int beg = o[node], end = o[node + 1];
    const int* ent = entries + (size_t)(b * 2 + dir) * EE;
    const float4* bias4 = (const float4*)bias;
    float4 acc = {0.f, 0.f, 0.f, 0.f};
    for (int p = beg; p < end; ++p) {
        int e2 = ent[p];
        int row = e2 >> 4, t = e2 & 15;
        ushort4 pv = *(const ushort4*)(msgs + (size_t)row * DD + lane * 4);
        float4 bv = bias4[t * 64 + lane];
        acc.x += bf2f(pv.x) + bv.x;
        acc.y += bf2f(pv.y) + bv.y;
        acc.z += bf2f(pv.z) + bv.z;
        acc.w += bf2f(pv.w) + bv.w;
    }
    ushort4 o4;
    o4.x = f2bf(acc.x); o4.y = f2bf(acc.y); o4.z = f2bf(acc.z); o4.w = f2bf(acc.w);
    int colbase = (dir == 0 ? 256 : 0) + lane * 4;
    *(ushort4*)(Xb + ((size_t)b * NN + node) * 768 + colbase) = o4;
}

// ---------------- final attention readout ----------------
__global__ void final_reduce(const float* __restrict__ h, const float* __restrict__ ann,
                             const float* __restrict__ Wa, const float* __restrict__ ba,
                             const float* __restrict__ Wo, const float* __restrict__ bo,
                             float* __restrict__ acc) {
    int wv = threadIdx.x >> 6, lane = threadIdx.x & 63;
    int b = blockIdx.x >> 5;
    int nbase = (blockIdx.x & 31) * 128 + wv * 32;
    float4 wah = ((const float4*)Wa)[lane];
    float4 woh = ((const float4*)Wo)[lane];
    float4 waa = {0, 0, 0, 0}, woa = {0, 0, 0, 0};
    if (lane < 16) {
        waa = ((const float4*)(Wa + 256))[lane];
        woa = ((const float4*)(Wo + 256))[lane];
    }
    float bav = ba[0], bov = bo[0];
    float part = 0.f;
    for (int it = 0; it < 32; ++it) {
        int node = nbase + it;
        float4 hv = ((const float4*)(h + ((size_t)b * NN + node) * DD))[lane];
        float sa = hv.x * wah.x + hv.y * wah.y + hv.z * wah.z + hv.w * wah.w;
        float so = hv.x * woh.x + hv.y * woh.y + hv.z * woh.z + hv.w * woh.w;
        if (lane < 16) {
            float4 av = ((const float4*)(ann + ((size_t)b * NN + node) * ADIM))[lane];
            sa += av.x * waa.x + av.y * waa.y + av.z * waa.z + av.w * waa.w;
            so += av.x * woa.x + av.y * woa.y + av.z * woa.z + av.w * woa.w;
        }
        for (int off = 32; off; off >>= 1) {
            sa += __shfl_down(sa, off);
            so += __shfl_down(so, off);
        }
        if (lane == 0) part += sigmoidf_(sa + bav) * tanhf(so + bov);
    }
    if (lane == 0) atomicAdd(&acc[b], part);
}

__global__ void final_out(const float* __restrict__ acc, float* __restrict__ out) {
    int b = threadIdx.x;
    if (b < BB) out[b] = sigmoidf_(acc[b]);
}

extern "C" void kernel_launch(void* const* d_in, const int* in_sizes, int n_in,
                              void* d_out, int out_size, void* d_ws, size_t ws_size,
                              hipStream_t stream) {
    const int*   ann_id     = (const int*)d_in[0];
    const int*   src        = (const int*)d_in[1];
    const int*   dst        = (const int*)d_in[2];
    const int*   etype      = (const int*)d_in[3];
    const float* edge_embed = (const float*)d_in[4];
    const float* edge_bias  = (const float*)d_in[5];
    const float* type_embed = (const float*)d_in[6];
    const float* Wr = (const float*)d_in[7];
    const float* br = (const float*)d_in[8];
    const float* Wz = (const float*)d_in[9];
    const float* bz = (const float*)d_in[10];
    const float* Wh = (const float*)d_in[11];
    const float* bh = (const float*)d_in[12];
    const float* Wa = (const float*)d_in[13];
    const float* ba = (const float*)d_in[14];
    const float* Wo = (const float*)d_in[15];
    const float* bo = (const float*)d_in[16];
    float* out = (float*)d_out;

    char* base = (char*)d_ws;
    size_t off = 0;
    auto alloc = [&](size_t bytes) { char* p = base + off; off += (bytes + 255) & ~(size_t)255; return p; };
    float* ann  = (float*)alloc((size_t)BB * NN * ADIM * 4);          // 4 MB
    float* h    = (float*)alloc((size_t)BB * NN * DD * 4);            // 16 MB
    float* acc  = (float*)alloc(64);
    unsigned short* h_bf   = (unsigned short*)alloc((size_t)BB * NN * DD * 2);   // 8 MB
    unsigned short* W2bf   = (unsigned short*)alloc((size_t)TT * DD * DD * 2);   // 2 MB
    unsigned short* Wcatbf = (unsigned short*)alloc(768 * 768 * 2);
    unsigned short* Whhbf  = (unsigned short*)alloc(256 * 256 * 2);
    unsigned short* msgs   = (unsigned short*)alloc((size_t)MAXM * DD * 2);      // 71 MB
    unsigned short* Xbf    = (unsigned short*)alloc((size_t)BB * NN * 768 * 2);  // 24 MB
    unsigned short* RHbf   = (unsigned short*)alloc((size_t)BB * NN * DD * 2);   // 8 MB
    unsigned short* Zb     = (unsigned short*)alloc((size_t)BB * NN * DD * 2);   // 8 MB
    unsigned short* Ub     = (unsigned short*)alloc((size_t)BB * NN * DD * 2);   // 8 MB
    int* counts  = (int*)alloc((size_t)BB * 2 * NN * 4);              // 128 KB
    int* c32     = (int*)alloc(1024 * 4);                             // 64 bins x 16 ints
    int* cursor  = (int*)alloc((size_t)BB * 2 * NN * 4);
    int* offsets = (int*)alloc((size_t)BB * 2 * OSTRIDE * 4);
    int* entries = (int*)alloc((size_t)BB * 2 * EE * 4);              // 512 KB
    int* tcur    = (int*)alloc(64 * 4);
    int* ttype   = (int*)alloc(MAXTILES * 4);
    int* idx2    = (int*)alloc((size_t)MAXM * 4);                     // 557 KB
    int* map     = (int*)alloc((size_t)262144 * 4);                   // 1 MB
    // total ~153 MB

    // ---- prep (once per call) ----
    prep_kernel<<<dim3(7680), dim3(256), 0, stream>>>(
        ann_id, type_embed, edge_embed, Wr, Wz, Wh,
        ann, h, h_bf, Xbf, W2bf, Wcatbf, Whhbf, acc, counts, c32, map);
    claim_kernel<<<dim3((BB * EE) / 256), dim3(256), 0, stream>>>(
        src, dst, etype, counts, c32, map);
    scan_kernel<<<dim3(BB * 2), dim3(1024), 0, stream>>>(counts, offsets, cursor);
    scan2_kernel<<<dim3(1), dim3(64), 0, stream>>>(c32, tcur, ttype, idx2);
    fill3_kernel<<<dim3((BB * EE) / 256), dim3(256), 0, stream>>>(
        src, dst, etype, tcur, cursor, entries, idx2, map);

    for (int s = 0; s < STEPS; ++s) {
        gemm_msgs<<<dim3(MAXTILES * 4), dim3(256), 0, stream>>>(
            h_bf, W2bf, idx2, ttype, msgs);
        gather2_kernel<<<dim3(BB * 2 * NN / 4), dim3(256), 0, stream>>>(
            msgs, offsets, entries, edge_bias, Xbf);
        gemm_rzu<<<dim3(1536), dim3(256), 0, stream>>>(
            Xbf, Wcatbf, br, bz, h, RHbf, Zb, Ub);
        gemm_hh<<<dim3(1024), dim3(256), 0, stream>>>(
            RHbf, Whhbf, Zb, Ub, bh, h, h_bf, Xbf);
    }

    final_reduce<<<dim3(128), dim3(256), 0, stream>>>(h, ann, Wa, ba, Wo, bo, acc);
    final_out<<<dim3(1), dim3(64), 0, stream>>>(acc, out);
}

// Round 19
// 400.028 us; speedup vs baseline: 1.1792x; 1.0285x over previous
//
#include <hip/hip_runtime.h>
#include <cstdint>

#define BB 4
#define NN 4096
#define EE 16384
#define DD 256
#define ADIM 64
#define TT 16
#define HALFE 8
#define STEPS 3
#define OSTRIDE 4160
#define MAXTILES 1088            // 128-row msg tiles (uniques <= 139264 padded worst case)
#define MAXM (MAXTILES * 128)

#define AS1 __attribute__((address_space(1)))
#define AS3 __attribute__((address_space(3)))

typedef __attribute__((ext_vector_type(8))) short short8;
typedef __attribute__((ext_vector_type(4))) float f32x4;

__device__ __forceinline__ float sigmoidf_(float x) { return 1.0f / (1.0f + __expf(-x)); }

__device__ __forceinline__ unsigned short f2bf(float x) {
    unsigned u = __float_as_uint(x);
    u += 0x7fffu + ((u >> 16) & 1u);
    return (unsigned short)(u >> 16);
}
__device__ __forceinline__ float bf2f(unsigned short b) {
    return __uint_as_float(((unsigned)b) << 16);
}

// ---------------- fused prep: init + conv(W2) + wcat + whh + zero(acc,counts,c32,map) ----------------
__global__ void prep_kernel(const int* __restrict__ ann_id, const float* __restrict__ type_embed,
                            const float* __restrict__ edge_embed, const float* __restrict__ Wr,
                            const float* __restrict__ Wz, const float* __restrict__ Wh,
                            float* __restrict__ ann, float* __restrict__ h,
                            unsigned short* __restrict__ hbf, unsigned short* __restrict__ Xbf,
                            unsigned short* __restrict__ W2bf, unsigned short* __restrict__ Wcatbf,
                            unsigned short* __restrict__ Whhbf, float* __restrict__ acc,
                            int* __restrict__ counts, int* __restrict__ c32,
                            int* __restrict__ map) {
    int bid = blockIdx.x, tid = threadIdx.x;
    if (bid < 4096) {                           // init: B*N*64 threads, 4 elems each
        if (bid < 128) counts[bid * 256 + tid] = 0;
        if (bid < 1024) map[bid * 256 + tid] = -1;
        if (bid == 0) { c32[tid] = 0; c32[256 + tid] = 0; c32[512 + tid] = 0; c32[768 + tid] = 0; }
        if (bid == 0 && tid < 16) acc[tid] = 0.f;
        int idx = bid * 256 + tid;
        int bn = idx >> 6, q = idx & 63;
        int id = ann_id[bn];
        float4 v = {0.f, 0.f, 0.f, 0.f};
        if (q < 16) {
            if (id > 0) v = ((const float4*)(type_embed + (size_t)(id - 1) * ADIM))[q];
            ((float4*)(ann + (size_t)bn * ADIM))[q] = v;
        }
        ((float4*)(h + (size_t)bn * DD))[q] = v;
        ushort4 o;
        o.x = f2bf(v.x); o.y = f2bf(v.y); o.z = f2bf(v.z); o.w = f2bf(v.w);
        ((ushort4*)(hbf + (size_t)bn * DD))[q] = o;
        ((ushort4*)(Xbf + (size_t)bn * 768 + 512))[q] = o;
    } else if (bid < 5120) {                    // conv edge_embed -> W2bf, 4 elems each
        int idx = (bid - 4096) * 256 + tid;
        float4 v = ((const float4*)edge_embed)[idx];
        ushort4 o;
        o.x = f2bf(v.x); o.y = f2bf(v.y); o.z = f2bf(v.z); o.w = f2bf(v.w);
        ((ushort4*)W2bf)[idx] = o;
    } else if (bid < 7424) {                    // Wcat_t[c][k]
        int idx = (bid - 5120) * 256 + tid;     // 768*768
        int c = idx / 768, k = idx % 768;
        float v;
        if (c < 256)       v = Wr[c * 768 + k];
        else if (c < 512)  v = Wz[(c - 256) * 768 + k];
        else               v = (k < 512) ? Wh[(c - 512) * 768 + k] : 0.f;
        Wcatbf[idx] = f2bf(v);
    } else {                                    // Whh_t[i][k] = Wh[i][512+k]
        int idx = (bid - 7424) * 256 + tid;     // 256*256
        int i = idx / 256, k = idx % 256;
        Whhbf[idx] = f2bf(Wh[i * 768 + 512 + k]);
    }
}

// ---------------- claim: node-degree counts + dedup-claim unique (b,t16,nbr) keys ----------------
__global__ void claim_kernel(const int* __restrict__ src, const int* __restrict__ dst,
                             const int* __restrict__ et, int* __restrict__ counts,
                             int* __restrict__ c32, int* __restrict__ map) {
    __shared__ int cnt[64];
    __shared__ int bse[64];
    int tid = threadIdx.x;
    if (tid < 64) cnt[tid] = 0;
    __syncthreads();
    int idx = blockIdx.x * 256 + tid;           // B*E
    int b = idx >> 14;
    int s = src[idx], d = dst[idx], t = et[idx];
    atomicAdd(&counts[(b * 2 + 0) * NN + s], 1);
    atomicAdd(&counts[(b * 2 + 1) * NN + d], 1);
    int bin0 = b * 16 + t;
    int bin1 = b * 16 + 8 + t;
    int k0 = (b << 16) | (t << 12) | d;          // dir-out msg: W[t] @ h[d]
    int k1 = (b << 16) | ((t + 8) << 12) | s;    // dir-in  msg: W[t+8] @ h[s]
    bool w0 = (atomicCAS(&map[k0], -1, -2) == -1);
    bool w1 = (atomicCAS(&map[k1], -1, -2) == -1);
    int r0 = w0 ? atomicAdd(&cnt[bin0], 1) : 0;
    int r1 = w1 ? atomicAdd(&cnt[bin1], 1) : 0;
    __syncthreads();
    if (tid < 64) bse[tid] = cnt[tid] ? atomicAdd(&c32[tid * 16], cnt[tid]) : 0;
    __syncthreads();
    if (w0) map[k0] = bse[bin0] + r0;
    if (w1) map[k1] = bse[bin1] + r1;
}

__global__ __launch_bounds__(1024) void scan_kernel(const int* __restrict__ counts,
                                                    int* __restrict__ offs,
                                                    int* __restrict__ cursor) {
    __shared__ int lsum[1024];
    int t = threadIdx.x, seg = blockIdx.x;      // 8 segments of 4096
    int4 v = ((const int4*)(counts + (size_t)seg * NN))[t];
    int s1 = v.x + v.y, s2 = s1 + v.z, s3 = s2 + v.w;
    lsum[t] = s3;
    __syncthreads();
    for (int off = 1; off < 1024; off <<= 1) {
        int tmp = (t >= off) ? lsum[t - off] : 0;
        __syncthreads();
        lsum[t] += tmp;
        __syncthreads();
    }
    int base = lsum[t] - s3;
    int* o = offs + (size_t)seg * OSTRIDE;
    o[4 * t] = base; o[4 * t + 1] = base + v.x; o[4 * t + 2] = base + s1; o[4 * t + 3] = base + s2;
    if (t == 1023) o[4096] = lsum[1023];
    int* c = cursor + (size_t)seg * NN;
    c[4 * t] = base; c[4 * t + 1] = base + v.x; c[4 * t + 2] = base + s1; c[4 * t + 3] = base + s2;
}

// type-major segments seg = b*16 + t16 (64 bins of unique counts), padded to 128;
// inits ttype=-1, zeroes idx2 pad rows.
__global__ void scan2_kernel(const int* __restrict__ c32, int* __restrict__ type_cursor,
                             int* __restrict__ tile_type, int* __restrict__ idx2) {
    __shared__ int pad[64];
    int t = threadIdx.x;                        // 0..63 = b*16 + t16
    for (int k = t; k < MAXTILES; k += 64) tile_type[k] = -1;
    __syncthreads();
    int cnt = c32[t * 16];
    int padded = ((cnt + 127) >> 7) << 7;
    pad[t] = padded;
    __syncthreads();
    int off = 0;
    for (int k = 0; k < t; ++k) off += pad[k];
    type_cursor[t] = off;
    int t16 = t & 15;
    int tile0 = off >> 7;
    for (int k = 0; k < (padded >> 7); ++k) tile_type[tile0 + k] = t16;
    for (int r = off + cnt; r < off + padded; ++r) idx2[r] = 0;
}

// per edge: look up dedup'd msg rows, write idx2 (dup-safe) + node-major entries
__global__ void fill3_kernel(const int* __restrict__ src, const int* __restrict__ dst,
                             const int* __restrict__ et, const int* __restrict__ type_cursor,
                             int* __restrict__ node_cursor, int* __restrict__ entries,
                             int* __restrict__ idx2, const int* __restrict__ map) {
    int idx = blockIdx.x * 256 + threadIdx.x;   // B*E
    int b = idx >> 14;
    int s = src[idx], d = dst[idx], t = et[idx];
    int k0 = (b << 16) | (t << 12) | d;
    int k1 = (b << 16) | ((t + 8) << 12) | s;
    int p0 = type_cursor[b * 16 + t] + map[k0];
    int p1 = type_cursor[b * 16 + t + 8] + map[k1];
    idx2[p0] = b * NN + d;
    idx2[p1] = b * NN + s;
    int q0 = atomicAdd(&node_cursor[(b * 2 + 0) * NN + s], 1);
    entries[(size_t)(b * 2 + 0) * EE + q0] = (p0 << 4) | t;
    int q1 = atomicAdd(&node_cursor[(b * 2 + 1) * NN + d], 1);
    entries[(size_t)(b * 2 + 1) * EE + q1] = (p1 << 4) | (t + 8);
}

// ============ counted-vmcnt 2-phase GEMM cores (R12 config: 4 waves, 128x64 / 64x64) ============
#define COMP_128x64(cb)                                                                 \
    _Pragma("unroll")                                                                   \
    for (int kk = 0; kk < 2; ++kk) {                                                    \
        short8 af[4], bfv[2];                                                           \
        _Pragma("unroll")                                                               \
        for (int m = 0; m < 4; ++m) {                                                   \
            int R = wr * 64 + m * 16 + lr;                                              \
            af[m] = *(const short8*)((const char*)As + (cb) * 16384 + R * 128 + (((kk * 4 + hi) ^ rx) << 4)); \
        }                                                                               \
        _Pragma("unroll")                                                               \
        for (int n = 0; n < 2; ++n) {                                                   \
            int R = wc * 32 + n * 16 + lr;                                              \
            bfv[n] = *(const short8*)((const char*)Bs + (cb) * 8192 + R * 128 + (((kk * 4 + hi) ^ rx) << 4)); \
        }                                                                               \
        _Pragma("unroll")                                                               \
        for (int m = 0; m < 4; ++m)                                                     \
            _Pragma("unroll")                                                           \
            for (int n = 0; n < 2; ++n)                                                 \
                acc[m][n] = __builtin_amdgcn_mfma_f32_16x16x32_bf16(bfv[n], af[m], acc[m][n], 0, 0, 0); \
    }

#define PIPE_WAIT(NSTR)                                                                 \
    asm volatile("s_waitcnt vmcnt(" NSTR ")" ::: "memory");                             \
    __builtin_amdgcn_s_barrier();                                                       \
    __builtin_amdgcn_sched_barrier(0);

// ---------------- message GEMM: msgs[p] = h_bf[idx2[p]] @ W[tile_type]^T ----------------
// grid = MAXTILES*4 (128x64 tiles), K=256 -> 4 tiles, 6 loads/tile
__global__ __launch_bounds__(256) void gemm_msgs(const unsigned short* __restrict__ A,
                                                 const unsigned short* __restrict__ W2,
                                                 const int* __restrict__ idx2,
                                                 const int* __restrict__ tile_type,
                                                 unsigned short* __restrict__ C) {
    __shared__ __align__(16) unsigned short As[2 * 128 * 64];
    __shared__ __align__(16) unsigned short Bs[2 * 64 * 64];
    const int bid = blockIdx.x;
    const int wg = (bid & 7) * (MAXTILES * 4 / 8) + (bid >> 3);   // XCD-chunked
    const int by = wg >> 2, bx = wg & 3;
    const int t16 = tile_type[by];
    if (t16 < 0) return;
    const int r0 = by << 7, c0 = bx << 6;
    const int tid = threadIdx.x;
    const int wv = tid >> 6, lane = tid & 63;
    const int wr = wv >> 1, wc = wv & 1;
    const int lr = lane & 15, hi = lane >> 4, rx = lane & 7;
    const int strow = tid >> 3;                 // stage row 0..31 (wv*8 + lane>>3)
    const int scol = ((tid & 7) ^ ((tid >> 3) & 7)) << 3;
    int ar[4];
#pragma unroll
    for (int i = 0; i < 4; ++i) ar[i] = idx2[r0 + strow + i * 32];
    const unsigned short* Bg = W2 + (size_t)t16 * (DD * DD) + (size_t)(c0 + strow) * DD + scol;
    f32x4 acc[4][2] = {};
#define MS_STG(buf, kof)                                                                \
    { _Pragma("unroll")                                                                 \
      for (int i = 0; i < 4; ++i)                                                       \
          __builtin_amdgcn_global_load_lds(                                             \
              (const AS1 void*)(A + (size_t)ar[i] * DD + scol + (kof)),                 \
              (AS3 void*)((char*)As + (buf) * 16384 + wv * 1024 + i * 4096), 16, 0, 0); \
      __builtin_amdgcn_global_load_lds(                                                 \
          (const AS1 void*)(Bg + (kof)),                                                \
          (AS3 void*)((char*)Bs + (buf) * 8192 + wv * 1024), 16, 0, 0);                 \
      __builtin_amdgcn_global_load_lds(                                                 \
          (const AS1 void*)(Bg + (size_t)32 * DD + (kof)),                              \
          (AS3 void*)((char*)Bs + (buf) * 8192 + wv * 1024 + 4096), 16, 0, 0); }
    MS_STG(0, 0)
    for (int it = 0; it < 3; ++it) {
        MS_STG((it + 1) & 1, (it + 1) * 64)
        PIPE_WAIT("6")
        COMP_128x64(it & 1)
        __builtin_amdgcn_s_barrier();
    }
    PIPE_WAIT("0")
    COMP_128x64(1)
    const int erow = r0 + wr * 64 + lr;
    const int ecol = c0 + wc * 32 + (hi << 2);
#pragma unroll
    for (int m = 0; m < 4; ++m)
#pragma unroll
        for (int n = 0; n < 2; ++n) {
            ushort4 o;
            o.x = f2bf(acc[m][n][0]); o.y = f2bf(acc[m][n][1]);
            o.z = f2bf(acc[m][n][2]); o.w = f2bf(acc[m][n][3]);
            *(ushort4*)&C[(size_t)(erow + m * 16) * DD + ecol + n * 16] = o;
        }
}

// ---------------- RZU GEMM with fused GRU-gate epilogue (128x64, K=768 -> 12 tiles) ----------------
__global__ __launch_bounds__(256) void gemm_rzu(const unsigned short* __restrict__ A,
                                                const unsigned short* __restrict__ Bt,
                                                const float* __restrict__ br,
                                                const float* __restrict__ bz,
                                                const float* __restrict__ h,
                                                unsigned short* __restrict__ RH,
                                                unsigned short* __restrict__ Zb,
                                                unsigned short* __restrict__ Ub) {
    __shared__ __align__(16) unsigned short As[2 * 128 * 64];
    __shared__ __align__(16) unsigned short Bs[2 * 64 * 64];
    const int bid = blockIdx.x;
    const int wg = (bid & 7) * 192 + (bid >> 3);   // nwg=1536, XCD-chunked
    const int bx = wg % 12, by = wg / 12;
    const int r0 = by << 7, c0 = bx << 6;
    const int tid = threadIdx.x;
    const int wv = tid >> 6, lane = tid & 63;
    const int wr = wv >> 1, wc = wv & 1;
    const int lr = lane & 15, hi = lane >> 4, rx = lane & 7;
    const int strow = tid >> 3;
    const int scol = ((tid & 7) ^ ((tid >> 3) & 7)) << 3;
    const unsigned short* Ag = A + (size_t)(r0 + strow) * 768 + scol;
    const unsigned short* Bg = Bt + (size_t)(c0 + strow) * 768 + scol;
    f32x4 acc[4][2] = {};
#define RZ_STG(buf, kof)                                                                \
    { _Pragma("unroll")                                                                 \
      for (int i = 0; i < 4; ++i)                                                       \
          __builtin_amdgcn_global_load_lds(                                             \
              (const AS1 void*)(Ag + (size_t)(i * 32) * 768 + (kof)),                   \
              (AS3 void*)((char*)As + (buf) * 16384 + wv * 1024 + i * 4096), 16, 0, 0); \
      __builtin_amdgcn_global_load_lds(                                                 \
          (const AS1 void*)(Bg + (kof)),                                                \
          (AS3 void*)((char*)Bs + (buf) * 8192 + wv * 1024), 16, 0, 0);                 \
      __builtin_amdgcn_global_load_lds(                                                 \
          (const AS1 void*)(Bg + (size_t)32 * 768 + (kof)),                             \
          (AS3 void*)((char*)Bs + (buf) * 8192 + wv * 1024 + 4096), 16, 0, 0); }
    RZ_STG(0, 0)
    for (int it = 0; it < 11; ++it) {
        RZ_STG((it + 1) & 1, (it + 1) * 64)
        PIPE_WAIT("6")
        COMP_128x64(it & 1)
        __builtin_amdgcn_s_barrier();
    }
    PIPE_WAIT("0")
    COMP_128x64(1)
    const int erow = r0 + wr * 64 + lr;
    const int ecol = c0 + wc * 32 + (hi << 2);
    const int region = c0 >> 8;
#pragma unroll
    for (int m = 0; m < 4; ++m)
#pragma unroll
        for (int n = 0; n < 2; ++n) {
            int gr = erow + m * 16;
            int gc = ecol + n * 16;
            f32x4 v = acc[m][n];
            if (region == 0) {
                float4 bb = *(const float4*)&br[gc];
                float4 hv = *(const float4*)&h[(size_t)gr * 256 + gc];
                ushort4 o;
                o.x = f2bf(sigmoidf_(v[0] + bb.x) * hv.x);
                o.y = f2bf(sigmoidf_(v[1] + bb.y) * hv.y);
                o.z = f2bf(sigmoidf_(v[2] + bb.z) * hv.z);
                o.w = f2bf(sigmoidf_(v[3] + bb.w) * hv.w);
                *(ushort4*)&RH[(size_t)gr * 256 + gc] = o;
            } else if (region == 1) {
                int c = gc - 256;
                float4 bb = *(const float4*)&bz[c];
                ushort4 o;
                o.x = f2bf(sigmoidf_(v[0] + bb.x));
                o.y = f2bf(sigmoidf_(v[1] + bb.y));
                o.z = f2bf(sigmoidf_(v[2] + bb.z));
                o.w = f2bf(sigmoidf_(v[3] + bb.w));
                *(ushort4*)&Zb[(size_t)gr * 256 + c] = o;
            } else {
                int c = gc - 512;
                ushort4 o;
                o.x = f2bf(v[0]); o.y = f2bf(v[1]); o.z = f2bf(v[2]); o.w = f2bf(v[3]);
                *(ushort4*)&Ub[(size_t)gr * 256 + c] = o;
            }
        }
}

// ---------------- HH GEMM with fused h-update epilogue (64x64, K=256 -> 4 tiles) ----------------
__global__ __launch_bounds__(256) void gemm_hh(const unsigned short* __restrict__ A,
                                               const unsigned short* __restrict__ Bt,
                                               const unsigned short* __restrict__ Zb,
                                               const unsigned short* __restrict__ Ub,
                                               const float* __restrict__ bh,
                                               float* __restrict__ h,
                                               unsigned short* __restrict__ hbf,
                                               unsigned short* __restrict__ Xbf) {
    __shared__ __align__(16) unsigned short As[2 * 64 * 64];
    __shared__ __align__(16) unsigned short Bs[2 * 64 * 64];
    const int bid = blockIdx.x;
    const int wg = (bid & 7) * 128 + (bid >> 3);   // nwg=1024, XCD-chunked
    const int r0 = wg >> 2 << 6, c0 = (wg & 3) << 6;
    const int tid = threadIdx.x;
    const int wv = tid >> 6, lane = tid & 63;
    const int wr = wv >> 1, wc = wv & 1;
    const int lr = lane & 15, hi = lane >> 4, rx = lane & 7;
    const int srow = wv * 8 + (lane >> 3);
    const int scol = ((lane & 7) ^ (lane >> 3)) << 3;
    const unsigned short* Ag = A + (size_t)(r0 + srow) * 256 + scol;
    const unsigned short* Bg = Bt + (size_t)(c0 + srow) * 256 + scol;
    f32x4 acc[2][2] = {};
#define HH_STG(buf, kof)                                                                \
    { _Pragma("unroll")                                                                 \
      for (int i = 0; i < 2; ++i) {                                                     \
          __builtin_amdgcn_global_load_lds(                                             \
              (const AS1 void*)(Ag + (size_t)(i * 32) * 256 + (kof)),                   \
              (AS3 void*)((char*)As + (buf) * 8192 + wv * 1024 + i * 4096), 16, 0, 0);  \
          __builtin_amdgcn_global_load_lds(                                             \
              (const AS1 void*)(Bg + (size_t)(i * 32) * 256 + (kof)),                   \
              (AS3 void*)((char*)Bs + (buf) * 8192 + wv * 1024 + i * 4096), 16, 0, 0); } }
#define COMP_64x64(cb)                                                                  \
    _Pragma("unroll")                                                                   \
    for (int kk = 0; kk < 2; ++kk) {                                                    \
        short8 af[2], bfv[2];                                                           \
        _Pragma("unroll")                                                               \
        for (int m = 0; m < 2; ++m) {                                                   \
            int R = wr * 32 + m * 16 + lr;                                              \
            af[m] = *(const short8*)((const char*)As + (cb) * 8192 + R * 128 + (((kk * 4 + hi) ^ rx) << 4)); \
        }                                                                               \
        _Pragma("unroll")                                                               \
        for (int n = 0; n < 2; ++n) {                                                   \
            int R = wc * 32 + n * 16 + lr;                                              \
            bfv[n] = *(const short8*)((const char*)Bs + (cb) * 8192 + R * 128 + (((kk * 4 + hi) ^ rx) << 4)); \
        }                                                                               \
        _Pragma("unroll")                                                               \
        for (int m = 0; m < 2; ++m)                                                     \
            _Pragma("unroll")                                                           \
            for (int n = 0; n < 2; ++n)                                                 \
                acc[m][n] = __builtin_amdgcn_mfma_f32_16x16x32_bf16(bfv[n], af[m], acc[m][n], 0, 0, 0); \
    }
    HH_STG(0, 0)
    for (int it = 0; it < 3; ++it) {
        HH_STG((it + 1) & 1, (it + 1) * 64)
        PIPE_WAIT("4")
        COMP_64x64(it & 1)
        __builtin_amdgcn_s_barrier();
    }
    PIPE_WAIT("0")
    COMP_64x64(1)
    const int erow = r0 + wr * 32 + lr;
    const int ecol = c0 + wc * 32 + (hi << 2);
#pragma unroll
    for (int m = 0; m < 2; ++m)
#pragma unroll
        for (int n = 0; n < 2; ++n) {
            int gr = erow + m * 16;
            int gc = ecol + n * 16;
            size_t base = (size_t)gr * 256 + gc;
            f32x4 v = acc[m][n];
            float4 bb = *(const float4*)&bh[gc];
            float4 hv = *(const float4*)&h[base];
            ushort4 zp = *(const ushort4*)&Zb[base];
            ushort4 up = *(const ushort4*)&Ub[base];
            float4 hn;
            {
                float z = bf2f(zp.x); hn.x = (1.f - z) * hv.x + z * tanhf(bf2f(up.x) + v[0] + bb.x);
            }{
                float z = bf2f(zp.y); hn.y = (1.f - z) * hv.y + z * tanhf(bf2f(up.y) + v[1] + bb.y);
            }{
                float z = bf2f(zp.z); hn.z = (1.f - z) * hv.z + z * tanhf(bf2f(up.z) + v[2] + bb.z);
            }{
                float z = bf2f(zp.w); hn.w = (1.f - z) * hv.w + z * tanhf(bf2f(up.w) + v[3] + bb.w);
            }
            *(float4*)&h[base] = hn;
            ushort4 o;
            o.x = f2bf(hn.x); o.y = f2bf(hn.y); o.z = f2bf(hn.z); o.w = f2bf(hn.w);
            *(ushort4*)&hbf[base] = o;
            *(ushort4*)&Xbf[(size_t)gr * 768 + 512 + gc] = o;
        }
}

// ---------------- CSR gather: chunk-prefetched entry codes, bf16 out ----------------
__global__ void gather2_kernel(const unsigned short* __restrict__ msgs,
                               const int* __restrict__ offs, const int* __restrict__ entries,
                               const float* __restrict__ bias, unsigned short* __restrict__ Xb) {
    int wv = threadIdx.x >> 6, lane = threadIdx.x & 63;
    int slot = blockIdx.x * 4 + wv;             // [0, B*2*N)
    int b = slot >> 13;
    int dir = (slot >> 12) & 1;
    int node = slot & 4095;
    const int* o = offs + (size_t)(b * 2 + dir) * OSTRIDE;
    int beg = o[node], end = o[node + 1];
    const int* ent = entries + (size_t)(b * 2 + dir) * EE;
    const float4* bias4 = (const float4*)bias;
    float4 acc = {0.f, 0.f, 0.f, 0.f};
    int p = beg;
    while (p < end) {
        int nchunk = end - p;
        if (nchunk > 8) nchunk = 8;
        int codes[8];
#pragma unroll 8
        for (int i = 0; i < 8; ++i)
            if (i < nchunk) codes[i] = ent[p + i];
#pragma unroll 8
        for (int i = 0; i < 8; ++i) {
            if (i < nchunk) {
                int e2 = codes[i];
                int row = e2 >> 4, t = e2 & 15;
                ushort4 pv = *(const ushort4*)(msgs + (size_t)row * DD + lane * 4);
                float4 bv = bias4[t * 64 + lane];
                acc.x += bf2f(pv.x) + bv.x;
                acc.y += bf2f(pv.y) + bv.y;
                acc.z += bf2f(pv.z) + bv.z;
                acc.w += bf2f(pv.w) + bv.w;
            }
        }
        p += nchunk;
    }
    ushort4 o4;
    o4.x = f2bf(acc.x); o4.y = f2bf(acc.y); o4.z = f2bf(acc.z); o4.w = f2bf(acc.w);
    int colbase = (dir == 0 ? 256 : 0) + lane * 4;
    *(ushort4*)(Xb + ((size_t)b * NN + node) * 768 + colbase) = o4;
}

// ---------------- final attention readout ----------------
__global__ void final_reduce(const float* __restrict__ h, const float* __restrict__ ann,
                             const float* __restrict__ Wa, const float* __restrict__ ba,
                             const float* __restrict__ Wo, const float* __restrict__ bo,
                             float* __restrict__ acc) {
    int wv = threadIdx.x >> 6, lane = threadIdx.x & 63;
    int b = blockIdx.x >> 5;
    int nbase = (blockIdx.x & 31) * 128 + wv * 32;
    float4 wah = ((const float4*)Wa)[lane];
    float4 woh = ((const float4*)Wo)[lane];
    float4 waa = {0, 0, 0, 0}, woa = {0, 0, 0, 0};
    if (lane < 16) {
        waa = ((const float4*)(Wa + 256))[lane];
        woa = ((const float4*)(Wo + 256))[lane];
    }
    float bav = ba[0], bov = bo[0];
    float part = 0.f;
    for (int it = 0; it < 32; ++it) {
        int node = nbase + it;
        float4 hv = ((const float4*)(h + ((size_t)b * NN + node) * DD))[lane];
        float sa = hv.x * wah.x + hv.y * wah.y + hv.z * wah.z + hv.w * wah.w;
        float so = hv.x * woh.x + hv.y * woh.y + hv.z * woh.z + hv.w * woh.w;
        if (lane < 16) {
            float4 av = ((const float4*)(ann + ((size_t)b * NN + node) * ADIM))[lane];
            sa += av.x * waa.x + av.y * waa.y + av.z * waa.z + av.w * waa.w;
            so += av.x * woa.x + av.y * woa.y + av.z * woa.z + av.w * woa.w;
        }
        for (int off = 32; off; off >>= 1) {
            sa += __shfl_down(sa, off);
            so += __shfl_down(so, off);
        }
        if (lane == 0) part += sigmoidf_(sa + bav) * tanhf(so + bov);
    }
    if (lane == 0) atomicAdd(&acc[b], part);
}

__global__ void final_out(const float* __restrict__ acc, float* __restrict__ out) {
    int b = threadIdx.x;
    if (b < BB) out[b] = sigmoidf_(acc[b]);
}

extern "C" void kernel_launch(void* const* d_in, const int* in_sizes, int n_in,
                              void* d_out, int out_size, void* d_ws, size_t ws_size,
                              hipStream_t stream) {
    const int*   ann_id     = (const int*)d_in[0];
    const int*   src        = (const int*)d_in[1];
    const int*   dst        = (const int*)d_in[2];
    const int*   etype      = (const int*)d_in[3];
    const float* edge_embed = (const float*)d_in[4];
    const float* edge_bias  = (const float*)d_in[5];
    const float* type_embed = (const float*)d_in[6];
    const float* Wr = (const float*)d_in[7];
    const float* br = (const float*)d_in[8];
    const float* Wz = (const float*)d_in[9];
    const float* bz = (const float*)d_in[10];
    const float* Wh = (const float*)d_in[11];
    const float* bh = (const float*)d_in[12];
    const float* Wa = (const float*)d_in[13];
    const float* ba = (const float*)d_in[14];
    const float* Wo = (const float*)d_in[15];
    const float* bo = (const float*)d_in[16];
    float* out = (float*)d_out;

    char* base = (char*)d_ws;
    size_t off = 0;
    auto alloc = [&](size_t bytes) { char* p = base + off; off += (bytes + 255) & ~(size_t)255; return p; };
    float* ann  = (float*)alloc((size_t)BB * NN * ADIM * 4);          // 4 MB
    float* h    = (float*)alloc((size_t)BB * NN * DD * 4);            // 16 MB
    float* acc  = (float*)alloc(64);
    unsigned short* h_bf   = (unsigned short*)alloc((size_t)BB * NN * DD * 2);   // 8 MB
    unsigned short* W2bf   = (unsigned short*)alloc((size_t)TT * DD * DD * 2);   // 2 MB
    unsigned short* Wcatbf = (unsigned short*)alloc(768 * 768 * 2);
    unsigned short* Whhbf  = (unsigned short*)alloc(256 * 256 * 2);
    unsigned short* msgs   = (unsigned short*)alloc((size_t)MAXM * DD * 2);      // 71 MB
    unsigned short* Xbf    = (unsigned short*)alloc((size_t)BB * NN * 768 * 2);  // 24 MB
    unsigned short* RHbf   = (unsigned short*)alloc((size_t)BB * NN * DD * 2);   // 8 MB
    unsigned short* Zb     = (unsigned short*)alloc((size_t)BB * NN * DD * 2);   // 8 MB
    unsigned short* Ub     = (unsigned short*)alloc((size_t)BB * NN * DD * 2);   // 8 MB
    int* counts  = (int*)alloc((size_t)BB * 2 * NN * 4);              // 128 KB
    int* c32     = (int*)alloc(1024 * 4);                             // 64 bins x 16 ints
    int* cursor  = (int*)alloc((size_t)BB * 2 * NN * 4);
    int* offsets = (int*)alloc((size_t)BB * 2 * OSTRIDE * 4);
    int* entries = (int*)alloc((size_t)BB * 2 * EE * 4);              // 512 KB
    int* tcur    = (int*)alloc(64 * 4);
    int* ttype   = (int*)alloc(MAXTILES * 4);
    int* idx2    = (int*)alloc((size_t)MAXM * 4);                     // 557 KB
    int* map     = (int*)alloc((size_t)262144 * 4);                   // 1 MB
    // total ~153 MB

    // ---- prep (once per call) ----
    prep_kernel<<<dim3(7680), dim3(256), 0, stream>>>(
        ann_id, type_embed, edge_embed, Wr, Wz, Wh,
        ann, h, h_bf, Xbf, W2bf, Wcatbf, Whhbf, acc, counts, c32, map);
    claim_kernel<<<dim3((BB * EE) / 256), dim3(256), 0, stream>>>(
        src, dst, etype, counts, c32, map);
    scan_kernel<<<dim3(BB * 2), dim3(1024), 0, stream>>>(counts, offsets, cursor);
    scan2_kernel<<<dim3(1), dim3(64), 0, stream>>>(c32, tcur, ttype, idx2);
    fill3_kernel<<<dim3((BB * EE) / 256), dim3(256), 0, stream>>>(
        src, dst, etype, tcur, cursor, entries, idx2, map);

    for (int s = 0; s < STEPS; ++s) {
        gemm_msgs<<<dim3(MAXTILES * 4), dim3(256), 0, stream>>>(
            h_bf, W2bf, idx2, ttype, msgs);
        gather2_kernel<<<dim3(BB * 2 * NN / 4), dim3(256), 0, stream>>>(
            msgs, offsets, entries, edge_bias, Xbf);
        gemm_rzu<<<dim3(1536), dim3(256), 0, stream>>>(
            Xbf, Wcatbf, br, bz, h, RHbf, Zb, Ub);
        gemm_hh<<<dim3(1024), dim3(256), 0, stream>>>(
            RHbf, Whhbf, Zb, Ub, bh, h, h_bf, Xbf);
    }

    final_reduce<<<dim3(128), dim3(256), 0, stream>>>(h, ann, Wa, ba, Wo, bo, acc);
    final_out<<<dim3(1), dim3(64), 0, stream>>>(acc, out);
}